// Round 1
// baseline (3115.784 us; speedup 1.0000x reference)
//
#include <hip/hip_runtime.h>
#include <stdint.h>

typedef unsigned short u16;
typedef __bf16 bf16x8 __attribute__((ext_vector_type(8)));
typedef float f32x4 __attribute__((ext_vector_type(4)));

// LDS regions (u16 element offsets). 5 x 16384 u16 = 163840 B = full 160 KB.
#define LDS_TOK 0        // tokT [256 c][64 t]  col-major, xor-swizzled
#define LDS_Y   16384    // y    [64 t][256 c]  row-major, xor-swizzled (+ fp32 LN scratch)
#define LDS_Q   32768    // q / P(part0) / o
#define LDS_K   49152    // k / P(part1) / h_chunk
#define LDS_V   65536    // vT [8 h][32 d][64 s] xor-swizzled

__device__ __forceinline__ u16 f2b(float f) {
  union { float f; uint32_t u; } a; a.f = f;
  uint32_t r = a.u + 0x7fffu + ((a.u >> 16) & 1u);   // RNE, matches np/HW bf16
  return (u16)(r >> 16);
}
__device__ __forceinline__ float b2f(u16 u) {
  union { uint32_t u; float f; } a; a.u = ((uint32_t)u) << 16;
  return a.f;
}
// row-major [64][256] bf16, 16B chunks XORed by (row&7): 2-way max on frag reads
__device__ __forceinline__ int rowxor(int r, int c) {
  return (r << 8) + ((((c >> 3) ^ (r & 7)) << 3) | (c & 7));
}
// col-major token buffer [256 c][64 t], chunks (t>>3) XORed by (c&7)
__device__ __forceinline__ int tokidx(int c, int t) {
  return (c << 6) + ((((t >> 3) ^ (c & 7)) << 3) | (t & 7));
}
// vT [8][32][64]: chunks (s>>3) XORed by (dd&7)
__device__ __forceinline__ int vtidx(int h, int dd, int s) {
  return (h << 11) + (dd << 6) + ((((s >> 3) ^ (dd & 7)) << 3) | (s & 7));
}

// fp32 -> bf16 weight conversion into d_ws (runs every launch; stateless).
// layout: qkv_w[768*256] | proj_w[256*256] | fc1_w[1024*256] | fc2_w[256*1024]
__global__ void prep_weights(const float* __restrict__ qkv_w,
                             const float* __restrict__ proj_w,
                             const float* __restrict__ fc1_w,
                             const float* __restrict__ fc2_w,
                             u16* __restrict__ wbf) {
  int i = blockIdx.x * 1024 + threadIdx.x;   // grid covers exactly 786432
  float v;
  if (i < 196608)      v = qkv_w[i];
  else if (i < 262144) v = proj_w[i - 196608];
  else if (i < 524288) v = fc1_w[i - 262144];
  else                 v = fc2_w[i - 524288];
  wbf[i] = f2b(v);
}

__global__ __launch_bounds__(512) void winblock(
    const float* __restrict__ x, float* __restrict__ out,
    const u16* __restrict__ wbf,
    const float* __restrict__ qkv_b, const float* __restrict__ proj_b,
    const float* __restrict__ n1g, const float* __restrict__ n1b,
    const float* __restrict__ n2g, const float* __restrict__ n2b,
    const float* __restrict__ fc1b, const float* __restrict__ fc2b)
{
  __shared__ __align__(16) u16 lds[81920];  // 160 KB exactly -> 1 block/CU

  const int tid  = threadIdx.x;
  const int w    = tid >> 6;      // wave 0..7
  const int lane = tid & 63;
  const int l15  = lane & 15;
  const int quad = lane >> 4;

  const int win  = blockIdx.x;    // n = ((b*16 + wh)*16 + ww)
  const int bimg = win >> 8;
  const int wh   = (win >> 4) & 15;
  const int ww   = win & 15;

  const u16* wq = wbf;            // [768][256]
  const u16* wp = wbf + 196608;   // [256][256]
  const u16* w1 = wbf + 262144;   // [1024][256]
  const u16* w2 = wbf + 524288;   // [256][1024]

  // ---------------- load x window -> tokT (bf16) ----------------
  {
    const int cs = lane >> 3, i = lane & 7;     // lane = (c-sub, window row)
    for (int citer = 0; citer < 4; ++citer) {
      int c = w * 32 + citer * 8 + cs;
      const float* xp = x + ((((size_t)bimg * 256 + c) * 128 + wh * 8 + i) * 128 + ww * 8);
      float4 v0 = *(const float4*)xp;
      float4 v1 = *(const float4*)(xp + 4);
      union { bf16x8 v; u16 u[8]; } pk;
      pk.u[0] = f2b(v0.x); pk.u[1] = f2b(v0.y); pk.u[2] = f2b(v0.z); pk.u[3] = f2b(v0.w);
      pk.u[4] = f2b(v1.x); pk.u[5] = f2b(v1.y); pk.u[6] = f2b(v1.z); pk.u[7] = f2b(v1.w);
      // chunk for tokens t=i*8..i*8+7 of channel c
      *(bf16x8*)&lds[LDS_TOK + (c << 6) + ((i ^ (c & 7)) << 3)] = pk.v;
    }
  }
  __syncthreads();

  // ---------------- LayerNorm: tokT -> y (bf16) ----------------
  auto ln_pass = [&](const float* __restrict__ gp, const float* __restrict__ bp) {
    const int t = lane;
    float sum = 0.f, ss = 0.f;
    for (int cc = 0; cc < 32; ++cc) {
      int c = w * 32 + cc;
      float v = b2f(lds[LDS_TOK + tokidx(c, t)]);
      sum += v; ss += v * v;
    }
    float* yf = (float*)&lds[LDS_Y];           // transient fp32 scratch
    yf[w * 64 + t] = sum;
    yf[512 + w * 64 + t] = ss;
    __syncthreads();
    float tot = 0.f, tot2 = 0.f;
    for (int u = 0; u < 8; ++u) { tot += yf[u * 64 + t]; tot2 += yf[512 + u * 64 + t]; }
    float mu  = tot * (1.f / 256.f);
    float var = tot2 * (1.f / 256.f) - mu * mu;
    float rs  = rsqrtf(var + 1e-5f);
    __syncthreads();                            // partials read before y overwrites them
    for (int cc = 0; cc < 32; ++cc) {
      int c = w * 32 + cc;
      float v = b2f(lds[LDS_TOK + tokidx(c, t)]);
      lds[LDS_Y + rowxor(t, c)] = f2b((v - mu) * rs * gp[c] + bp[c]);
    }
    __syncthreads();
  };

  ln_pass(n1g, n1b);

  // ---------------- QKV GEMM: [64,256]x[768,256]^T ----------------
  {
    bf16x8 ay[4][8];                            // whole A in regs (128 VGPR)
    #pragma unroll
    for (int mt = 0; mt < 4; ++mt)
      #pragma unroll
      for (int ks = 0; ks < 8; ++ks)
        ay[mt][ks] = *(const bf16x8*)&lds[LDS_Y + rowxor(mt * 16 + l15, ks * 32 + quad * 8)];

    #pragma unroll 1
    for (int nt = 0; nt < 6; ++nt) {            // wave covers 6 of 48 n-tiles
      int ocol = (w * 6 + nt) * 16 + l15;       // 0..767
      f32x4 acc[4] = {{0,0,0,0},{0,0,0,0},{0,0,0,0},{0,0,0,0}};
      #pragma unroll
      for (int ks = 0; ks < 8; ++ks) {
        bf16x8 b = *(const bf16x8*)(wq + ocol * 256 + ks * 32 + quad * 8);
        #pragma unroll
        for (int mt = 0; mt < 4; ++mt)
          acc[mt] = __builtin_amdgcn_mfma_f32_16x16x32_bf16(ay[mt][ks], b, acc[mt], 0, 0, 0);
      }
      float bias = qkv_b[ocol];
      int seg = ocol >> 8, c = ocol & 255;      // wave-uniform per nt
      #pragma unroll
      for (int mt = 0; mt < 4; ++mt)
        #pragma unroll
        for (int r = 0; r < 4; ++r) {
          int t = mt * 16 + quad * 4 + r;
          u16 v = f2b(acc[mt][r] + bias);
          if (seg == 0)      lds[LDS_Q + rowxor(t, c)] = v;
          else if (seg == 1) lds[LDS_K + rowxor(t, c)] = v;
          else               lds[LDS_V + vtidx(c >> 5, c & 31, t)] = v;  // v stored transposed
        }
    }
  }
  __syncthreads();

  // ---------------- attention: wave w = head w ----------------
  {
    const int c0 = w * 32;
    bf16x8 aq[4], bk[4];
    #pragma unroll
    for (int mt = 0; mt < 4; ++mt)
      aq[mt] = *(const bf16x8*)&lds[LDS_Q + rowxor(mt * 16 + l15, c0 + quad * 8)];
    #pragma unroll
    for (int ns = 0; ns < 4; ++ns)
      bk[ns] = *(const bf16x8*)&lds[LDS_K + rowxor(ns * 16 + l15, c0 + quad * 8)];

    f32x4 sacc[4][4];
    #pragma unroll
    for (int mt = 0; mt < 4; ++mt)
      #pragma unroll
      for (int ns = 0; ns < 4; ++ns) {
        f32x4 z = {0,0,0,0};
        sacc[mt][ns] = __builtin_amdgcn_mfma_f32_16x16x32_bf16(aq[mt], bk[ns], z, 0, 0, 0);
      }

    const float SCALE = 0.17677669529663687f;   // 1/sqrt(32)
    float inv[4][4];
    #pragma unroll
    for (int mt = 0; mt < 4; ++mt)
      #pragma unroll
      for (int r = 0; r < 4; ++r) {
        float m = fmaxf(fmaxf(sacc[mt][0][r], sacc[mt][1][r]),
                        fmaxf(sacc[mt][2][r], sacc[mt][3][r]));
        m = fmaxf(m, __shfl_xor(m, 1)); m = fmaxf(m, __shfl_xor(m, 2));
        m = fmaxf(m, __shfl_xor(m, 4)); m = fmaxf(m, __shfl_xor(m, 8));
        float e[4], sum = 0.f;
        #pragma unroll
        for (int ns = 0; ns < 4; ++ns) { e[ns] = __expf((sacc[mt][ns][r] - m) * SCALE); sum += e[ns]; }
        sum += __shfl_xor(sum, 1); sum += __shfl_xor(sum, 2);
        sum += __shfl_xor(sum, 4); sum += __shfl_xor(sum, 8);
        inv[mt][r] = 1.f / sum;
        int t = mt * 16 + quad * 4 + r;
        // P parked in this head's (now dead) q/k column slices
        #pragma unroll
        for (int ns = 0; ns < 4; ++ns) {
          int s = ns * 16 + l15;
          int c = c0 + (s & 31);
          if (ns < 2) lds[LDS_Q + rowxor(t, c)] = f2b(e[ns]);
          else        lds[LDS_K + rowxor(t, c)] = f2b(e[ns]);
        }
      }
    __asm__ volatile("s_waitcnt lgkmcnt(0)" ::: "memory");  // P committed before re-read

    bf16x8 aP[4][2], bV[2][2];
    #pragma unroll
    for (int mt = 0; mt < 4; ++mt) {
      aP[mt][0] = *(const bf16x8*)&lds[LDS_Q + rowxor(mt * 16 + l15, c0 + quad * 8)];
      aP[mt][1] = *(const bf16x8*)&lds[LDS_K + rowxor(mt * 16 + l15, c0 + quad * 8)];
    }
    #pragma unroll
    for (int nd = 0; nd < 2; ++nd)
      #pragma unroll
      for (int ks = 0; ks < 2; ++ks) {
        int dd = nd * 16 + l15;
        bV[nd][ks] = *(const bf16x8*)&lds[LDS_V + (w << 11) + (dd << 6) +
                                         (((ks * 4 + quad) ^ (dd & 7)) << 3)];
      }
    f32x4 oacc[4][2];
    #pragma unroll
    for (int mt = 0; mt < 4; ++mt)
      #pragma unroll
      for (int nd = 0; nd < 2; ++nd) {
        f32x4 z = {0,0,0,0};
        z = __builtin_amdgcn_mfma_f32_16x16x32_bf16(aP[mt][0], bV[nd][0], z, 0, 0, 0);
        oacc[mt][nd] = __builtin_amdgcn_mfma_f32_16x16x32_bf16(aP[mt][1], bV[nd][1], z, 0, 0, 0);
      }
    // o overwrites this head's q slice (P already consumed)
    #pragma unroll
    for (int mt = 0; mt < 4; ++mt)
      #pragma unroll
      for (int nd = 0; nd < 2; ++nd)
        #pragma unroll
        for (int r = 0; r < 4; ++r) {
          int t = mt * 16 + quad * 4 + r;
          int c = c0 + nd * 16 + l15;
          lds[LDS_Q + rowxor(t, c)] = f2b(oacc[mt][nd][r] * inv[mt][r]);
        }
  }
  __syncthreads();

  // ---------------- proj GEMM + residual into tokT ----------------
  {
    bf16x8 ao[4][8];
    #pragma unroll
    for (int mt = 0; mt < 4; ++mt)
      #pragma unroll
      for (int ks = 0; ks < 8; ++ks)
        ao[mt][ks] = *(const bf16x8*)&lds[LDS_Q + rowxor(mt * 16 + l15, ks * 32 + quad * 8)];
    #pragma unroll 1
    for (int nt = 0; nt < 2; ++nt) {
      int ocol = (w * 2 + nt) * 16 + l15;
      f32x4 acc[4] = {{0,0,0,0},{0,0,0,0},{0,0,0,0},{0,0,0,0}};
      #pragma unroll
      for (int ks = 0; ks < 8; ++ks) {
        bf16x8 b = *(const bf16x8*)(wp + ocol * 256 + ks * 32 + quad * 8);
        #pragma unroll
        for (int mt = 0; mt < 4; ++mt)
          acc[mt] = __builtin_amdgcn_mfma_f32_16x16x32_bf16(ao[mt][ks], b, acc[mt], 0, 0, 0);
      }
      float bias = proj_b[ocol];
      #pragma unroll
      for (int mt = 0; mt < 4; ++mt)
        #pragma unroll
        for (int r = 0; r < 4; ++r) {
          int t = mt * 16 + quad * 4 + r;
          float v = acc[mt][r] + bias + b2f(lds[LDS_TOK + tokidx(ocol, t)]);
          lds[LDS_TOK + tokidx(ocol, t)] = f2b(v);
        }
    }
  }
  __syncthreads();

  ln_pass(n2g, n2b);

  // ---------------- MLP: fc1+GELU (chunks of 256 via k-buffer) + fc2 ----------------
  {
    bf16x8 ay[4][8];
    #pragma unroll
    for (int mt = 0; mt < 4; ++mt)
      #pragma unroll
      for (int ks = 0; ks < 8; ++ks)
        ay[mt][ks] = *(const bf16x8*)&lds[LDS_Y + rowxor(mt * 16 + l15, ks * 32 + quad * 8)];

    f32x4 oacc2[4][2];
    #pragma unroll
    for (int mt = 0; mt < 4; ++mt)
      #pragma unroll
      for (int nt = 0; nt < 2; ++nt)
        oacc2[mt][nt] = (f32x4){0,0,0,0};

    #pragma unroll 1
    for (int ch = 0; ch < 4; ++ch) {
      const int hb = ch * 256;
      // fc1 + exact GELU -> h_chunk (k region)
      #pragma unroll 1
      for (int nt = 0; nt < 2; ++nt) {
        int hcol = hb + (w * 2 + nt) * 16 + l15;
        f32x4 facc[4] = {{0,0,0,0},{0,0,0,0},{0,0,0,0},{0,0,0,0}};
        #pragma unroll
        for (int ks = 0; ks < 8; ++ks) {
          bf16x8 b = *(const bf16x8*)(w1 + hcol * 256 + ks * 32 + quad * 8);
          #pragma unroll
          for (int mt = 0; mt < 4; ++mt)
            facc[mt] = __builtin_amdgcn_mfma_f32_16x16x32_bf16(ay[mt][ks], b, facc[mt], 0, 0, 0);
        }
        float bias = fc1b[hcol];
        int hc = (w * 2 + nt) * 16 + l15;
        #pragma unroll
        for (int mt = 0; mt < 4; ++mt)
          #pragma unroll
          for (int r = 0; r < 4; ++r) {
            int t = mt * 16 + quad * 4 + r;
            float v = facc[mt][r] + bias;
            float g = 0.5f * v * (1.f + erff(v * 0.70710678118654752f));
            lds[LDS_K + rowxor(t, hc)] = f2b(g);
          }
      }
      __syncthreads();
      // fc2 partial accumulate
      #pragma unroll 1
      for (int nt = 0; nt < 2; ++nt) {
        int ocol = (w * 2 + nt) * 16 + l15;
        #pragma unroll
        for (int ks = 0; ks < 8; ++ks) {
          bf16x8 b = *(const bf16x8*)(w2 + ocol * 1024 + hb + ks * 32 + quad * 8);
          #pragma unroll
          for (int mt = 0; mt < 4; ++mt) {
            bf16x8 a = *(const bf16x8*)&lds[LDS_K + rowxor(mt * 16 + l15, ks * 32 + quad * 8)];
            oacc2[mt][nt] = __builtin_amdgcn_mfma_f32_16x16x32_bf16(a, b, oacc2[mt][nt], 0, 0, 0);
          }
        }
      }
      __syncthreads();
    }
    // fc2 epilogue: + bias + residual -> tokT (final result, bf16)
    #pragma unroll
    for (int nt = 0; nt < 2; ++nt) {
      int ocol = (w * 2 + nt) * 16 + l15;
      float bias = fc2b[ocol];
      #pragma unroll
      for (int mt = 0; mt < 4; ++mt)
        #pragma unroll
        for (int r = 0; r < 4; ++r) {
          int t = mt * 16 + quad * 4 + r;
          float v = oacc2[mt][nt][r] + bias + b2f(lds[LDS_TOK + tokidx(ocol, t)]);
          lds[LDS_TOK + tokidx(ocol, t)] = f2b(v);
        }
    }
  }
  __syncthreads();

  // ---------------- store tokT -> out (fp32) ----------------
  {
    const int cs = lane >> 3, i = lane & 7;
    for (int citer = 0; citer < 4; ++citer) {
      int c = w * 32 + citer * 8 + cs;
      union { bf16x8 v; u16 u[8]; } pk;
      pk.v = *(const bf16x8*)&lds[LDS_TOK + (c << 6) + ((i ^ (c & 7)) << 3)];
      float4 o0, o1;
      o0.x = b2f(pk.u[0]); o0.y = b2f(pk.u[1]); o0.z = b2f(pk.u[2]); o0.w = b2f(pk.u[3]);
      o1.x = b2f(pk.u[4]); o1.y = b2f(pk.u[5]); o1.z = b2f(pk.u[6]); o1.w = b2f(pk.u[7]);
      float* op = out + ((((size_t)bimg * 256 + c) * 128 + wh * 8 + i) * 128 + ww * 8);
      *(float4*)op = o0;
      *(float4*)(op + 4) = o1;
    }
  }
}

extern "C" void kernel_launch(void* const* d_in, const int* in_sizes, int n_in,
                              void* d_out, int out_size, void* d_ws, size_t ws_size,
                              hipStream_t stream) {
  const float* x      = (const float*)d_in[0];
  const float* qkv_w  = (const float*)d_in[1];
  const float* qkv_b  = (const float*)d_in[2];
  const float* proj_w = (const float*)d_in[3];
  const float* proj_b = (const float*)d_in[4];
  const float* n1g    = (const float*)d_in[5];
  const float* n1b    = (const float*)d_in[6];
  const float* n2g    = (const float*)d_in[7];
  const float* n2b    = (const float*)d_in[8];
  const float* fc1w   = (const float*)d_in[9];
  const float* fc1b   = (const float*)d_in[10];
  const float* fc2w   = (const float*)d_in[11];
  const float* fc2b   = (const float*)d_in[12];
  u16* wbf = (u16*)d_ws;   // needs 1,572,864 B of workspace

  prep_weights<<<768, 1024, 0, stream>>>(qkv_w, proj_w, fc1w, fc2w, wbf);
  winblock<<<4096, 512, 0, stream>>>(x, (float*)d_out, wbf,
                                     qkv_b, proj_b, n1g, n1b, n2g, n2b, fc1b, fc2b);
}